// Round 8
// baseline (269.310 us; speedup 1.0000x reference)
//
#include <hip/hip_runtime.h>
#include <hip/hip_fp16.h>
#include <stdint.h>

#define Bz 2
#define Tq 1024
#define Mm 1024
#define Hh 16
#define Ll 2048
#define Rr 3072

typedef __attribute__((ext_vector_type(8))) short bf16x8;
typedef __attribute__((ext_vector_type(4))) float f32x4;

typedef __attribute__((address_space(3))) uint8_t lds_u8_t;
typedef __attribute__((address_space(1))) uint8_t glb_u8_t;

__device__ __forceinline__ void gl2lds16(const void* g, void* l) {
  __builtin_amdgcn_global_load_lds((const glb_u8_t*)g, (lds_u8_t*)l, 16, 0, 0);
}

__device__ __forceinline__ unsigned short f2bf(float f) {
  unsigned int u = __builtin_bit_cast(unsigned int, f);
  u = u + 0x7fffu + ((u >> 16) & 1u);
  return (unsigned short)(u >> 16);
}
__device__ __forceinline__ float b2f(unsigned short s) {
  unsigned int u = ((unsigned int)s) << 16;
  return __builtin_bit_cast(float, u);
}

// ------- prep (merged): values cast | pos cast | mask bias | 5x W transpose -
// blocks: [0,4096) values, [4096,7168) pos, [7168,11264) mask (exactly
// 4,194,304 mask elems), [11264,12544) weight transpose (256 per matrix).
__global__ __launch_bounds__(256) void k_prep2(
    const float* __restrict__ x, const float* __restrict__ mem,
    const float* __restrict__ pos, const float* __restrict__ mask,
    const float* __restrict__ w0, const float* __restrict__ w1,
    const float* __restrict__ w2, const float* __restrict__ w3,
    const float* __restrict__ w4,
    unsigned short* __restrict__ vin, unsigned short* __restrict__ pb,
    unsigned short* __restrict__ mb,
    unsigned short* __restrict__ t0, unsigned short* __restrict__ t1,
    unsigned short* __restrict__ t2, unsigned short* __restrict__ t3,
    unsigned short* __restrict__ t4) {
  __shared__ float tile[64][65];
  int bid = blockIdx.x;
  if (bid < 4096) {
    int idx = bid * 256 + threadIdx.x;
    int e = idx << 2;
    int row = e >> 10, col = e & 1023;
    int b = row >> 11, l = row & 2047;
    const float* s = (l < Mm) ? (mem + (((size_t)b * Mm + l) << 10) + col)
                              : (x + (((size_t)b * Tq + (l - Mm)) << 10) + col);
    float4 v = *(const float4*)s;
    ushort4 o;
    o.x = f2bf(v.x); o.y = f2bf(v.y); o.z = f2bf(v.z); o.w = f2bf(v.w);
    *(ushort4*)(vin + e) = o;
  } else if (bid < 7168) {
    int idx = (bid - 4096) * 256 + threadIdx.x;
    int e = idx << 2;
    float4 v = *(const float4*)(pos + e);
    ushort4 t;
    t.x = f2bf(v.x); t.y = f2bf(v.y); t.z = f2bf(v.z); t.w = f2bf(v.w);
    *(ushort4*)(pb + e) = t;
  } else if (bid < 11264) {
    int idx = (bid - 7168) * 256 + threadIdx.x;
    int e = idx << 2;
    const float BIGM = 1.442695e30f;
    float4 v = *(const float4*)(mask + e);
    ushort4 t;
    t.x = f2bf((1.0f - v.x) * BIGM); t.y = f2bf((1.0f - v.y) * BIGM);
    t.z = f2bf((1.0f - v.z) * BIGM); t.w = f2bf((1.0f - v.w) * BIGM);
    *(ushort4*)(mb + e) = t;
  } else {
    int r3 = bid - 11264;
    int mz = r3 >> 8, rem = r3 & 255;
    const float* W;
    unsigned short* WT;
    switch (mz) {
      case 0: W = w0; WT = t0; break;
      case 1: W = w1; WT = t1; break;
      case 2: W = w2; WT = t2; break;
      case 3: W = w3; WT = t3; break;
      default: W = w4; WT = t4; break;
    }
    int k0 = (rem >> 4) * 64, n0 = (rem & 15) * 64;
    int tid = threadIdx.x;
    int rr = tid >> 4, c4 = (tid & 15) * 4;
#pragma unroll
    for (int it = 0; it < 4; ++it) {
      int r = rr + it * 16;
      float4 v = *(const float4*)(W + (size_t)(k0 + r) * 1024 + n0 + c4);
      tile[r][c4] = v.x; tile[r][c4 + 1] = v.y;
      tile[r][c4 + 2] = v.z; tile[r][c4 + 3] = v.w;
    }
    __syncthreads();
#pragma unroll
    for (int it = 0; it < 4; ++it) {
      int n = rr + it * 16;
      ushort4 o;
      o.x = f2bf(tile[c4 + 0][n]); o.y = f2bf(tile[c4 + 1][n]);
      o.z = f2bf(tile[c4 + 2][n]); o.w = f2bf(tile[c4 + 3][n]);
      *(ushort4*)(WT + (size_t)(n0 + n) * 1024 + k0 + c4) = o;
    }
  }
}

// ---------------- bf16 NT GEMM core (m97 structure, K=1024) -----------------
template <int RMAP>
__device__ __forceinline__ void gemm_core(const unsigned short* __restrict__ A,
                                          const unsigned short* __restrict__ Bt,
                                          int m0, int n0, unsigned short* As,
                                          unsigned short* Bs, f32x4 acc[4][4]) {
  const int tid = threadIdx.x;
  const int w = tid >> 6, lane = tid & 63;
  const int quad = lane >> 4, li = lane & 15;
  const int wr = w >> 1, wc = w & 1;
  f32x4 z = {0.f, 0.f, 0.f, 0.f};
#pragma unroll
  for (int mi = 0; mi < 4; ++mi)
#pragma unroll
    for (int ni = 0; ni < 4; ++ni) acc[mi][ni] = z;

  const int rs = lane >> 2;
  const int cs = lane & 3;

  for (int k0 = 0; k0 < 1024; k0 += 32) {
    __syncthreads();
#pragma unroll
    for (int s = 0; s < 2; ++s) {
      int i = w * 2 + s;
      int r = i * 16 + rs;
      int c = cs ^ ((r >> 1) & 3);
      int ar = m0 + r;
      if (RMAP) ar = ar + 1024 + (ar & 1024);
      gl2lds16(A + (size_t)ar * 1024 + k0 + c * 8, (char*)As + i * 1024);
      int br = n0 + r;
      gl2lds16(Bt + (size_t)br * 1024 + k0 + c * 8, (char*)Bs + i * 1024);
    }
    __syncthreads();
    bf16x8 af[4], bfr[4];
#pragma unroll
    for (int mi = 0; mi < 4; ++mi) {
      int r = wr * 64 + mi * 16 + li;
      int ch = quad ^ ((r >> 1) & 3);
      af[mi] = *(const bf16x8*)((const char*)As + r * 64 + ch * 16);
    }
#pragma unroll
    for (int ni = 0; ni < 4; ++ni) {
      int r = wc * 64 + ni * 16 + li;
      int ch = quad ^ ((r >> 1) & 3);
      bfr[ni] = *(const bf16x8*)((const char*)Bs + r * 64 + ch * 16);
    }
#pragma unroll
    for (int mi = 0; mi < 4; ++mi)
#pragma unroll
      for (int ni = 0; ni < 4; ++ni)
        acc[mi][ni] = __builtin_amdgcn_mfma_f32_16x16x32_bf16(
            af[mi], bfr[ni], acc[mi][ni], 0, 0, 0);
  }
}

// fused projections: [0,256) k|v DUAL (A staged once) | [256,384) q raw |
// [384,576) rk.  kv-dual: 12 frag reads feed 32 MFMAs (vs 16 in 2 blocks).
__global__ __launch_bounds__(256, 2) void k_proj(
    const unsigned short* __restrict__ Vin, const unsigned short* __restrict__ Pb,
    const unsigned short* __restrict__ WqT, const unsigned short* __restrict__ WkT,
    const unsigned short* __restrict__ WvT, const unsigned short* __restrict__ WrT,
    unsigned short* __restrict__ qb, unsigned short* __restrict__ kb,
    unsigned short* __restrict__ vtb, unsigned short* __restrict__ rkb) {
  __shared__ unsigned short As[128 * 32];
  __shared__ unsigned short Bs[128 * 32];   // Bk for dual; B for single
  __shared__ unsigned short Bs2[128 * 32];  // Bv for dual (unused otherwise)
  const int t = blockIdx.x;
  const int tid = threadIdx.x, w = tid >> 6, lane = tid & 63;
  const int quad = lane >> 4, li = lane & 15, wr = w >> 1, wc = w & 1;
  f32x4 z = {0.f, 0.f, 0.f, 0.f};

  if (t < 256) {  // k|v dual: M=4096, N=1024
    int m0 = (t >> 3) * 128, n0 = (t & 7) * 128;
    f32x4 ak[4][4], av[4][4];
#pragma unroll
    for (int mi = 0; mi < 4; ++mi)
#pragma unroll
      for (int ni = 0; ni < 4; ++ni) { ak[mi][ni] = z; av[mi][ni] = z; }
    const int rs = lane >> 2, cs = lane & 3;
    for (int k0 = 0; k0 < 1024; k0 += 32) {
      __syncthreads();
#pragma unroll
      for (int s = 0; s < 2; ++s) {
        int i = w * 2 + s;
        int r = i * 16 + rs;
        int c = cs ^ ((r >> 1) & 3);
        gl2lds16(Vin + (size_t)(m0 + r) * 1024 + k0 + c * 8, (char*)As + i * 1024);
        gl2lds16(WkT + (size_t)(n0 + r) * 1024 + k0 + c * 8, (char*)Bs + i * 1024);
        gl2lds16(WvT + (size_t)(n0 + r) * 1024 + k0 + c * 8, (char*)Bs2 + i * 1024);
      }
      __syncthreads();
      bf16x8 af[4], bk[4], bv[4];
#pragma unroll
      for (int mi = 0; mi < 4; ++mi) {
        int r = wr * 64 + mi * 16 + li;
        int ch = quad ^ ((r >> 1) & 3);
        af[mi] = *(const bf16x8*)((const char*)As + r * 64 + ch * 16);
      }
#pragma unroll
      for (int ni = 0; ni < 4; ++ni) {
        int r = wc * 64 + ni * 16 + li;
        int ch = quad ^ ((r >> 1) & 3);
        bk[ni] = *(const bf16x8*)((const char*)Bs + r * 64 + ch * 16);
        bv[ni] = *(const bf16x8*)((const char*)Bs2 + r * 64 + ch * 16);
      }
#pragma unroll
      for (int mi = 0; mi < 4; ++mi)
#pragma unroll
        for (int ni = 0; ni < 4; ++ni) {
          ak[mi][ni] = __builtin_amdgcn_mfma_f32_16x16x32_bf16(
              af[mi], bk[ni], ak[mi][ni], 0, 0, 0);
          av[mi][ni] = __builtin_amdgcn_mfma_f32_16x16x32_bf16(
              af[mi], bv[ni], av[mi][ni], 0, 0, 0);
        }
    }
#pragma unroll
    for (int mi = 0; mi < 4; ++mi)
#pragma unroll
      for (int ni = 0; ni < 4; ++ni) {
        int cc = n0 + wc * 64 + ni * 16 + li;
#pragma unroll
        for (int reg = 0; reg < 4; ++reg) {
          int rrow = m0 + wr * 64 + mi * 16 + quad * 4 + reg;
          kb[(size_t)rrow * 1024 + cc] = f2bf(ak[mi][ni][reg]);
        }
        int r0 = m0 + wr * 64 + mi * 16 + quad * 4;
        int b = r0 >> 11, l0 = r0 & 2047;
        ushort4 o;
        o.x = f2bf(av[mi][ni][0]); o.y = f2bf(av[mi][ni][1]);
        o.z = f2bf(av[mi][ni][2]); o.w = f2bf(av[mi][ni][3]);
        *(ushort4*)(vtb + ((size_t)(b * 1024 + cc)) * Ll + l0) = o;
      }
  } else if (t < 384) {  // q raw: M=2048 input rows
    int tt = t - 256;
    int m0 = (tt >> 3) * 128, n0 = (tt & 7) * 128;
    f32x4 acc[4][4];
    gemm_core<1>(Vin, WqT, m0, n0, As, Bs, acc);
#pragma unroll
    for (int mi = 0; mi < 4; ++mi)
#pragma unroll
      for (int ni = 0; ni < 4; ++ni)
#pragma unroll
        for (int reg = 0; reg < 4; ++reg) {
          int rrow = m0 + wr * 64 + mi * 16 + quad * 4 + reg;
          int cc = n0 + wc * 64 + ni * 16 + li;
          qb[(size_t)rrow * 1024 + cc] = f2bf(acc[mi][ni][reg]);
        }
  } else {  // rk: M=3072
    int tt = t - 384;
    int m0 = (tt >> 3) * 128, n0 = (tt & 7) * 128;
    f32x4 acc[4][4];
    gemm_core<0>(Pb, WrT, m0, n0, As, Bs, acc);
#pragma unroll
    for (int mi = 0; mi < 4; ++mi)
#pragma unroll
      for (int ni = 0; ni < 4; ++ni)
#pragma unroll
        for (int reg = 0; reg < 4; ++reg) {
          int rrow = m0 + wr * 64 + mi * 16 + quad * 4 + reg;
          int cc = n0 + wc * 64 + ni * 16 + li;
          rkb[(size_t)rrow * 1024 + cc] = f2bf(acc[mi][ni][reg]);
        }
  }
}

// output projection, 64x128 tile (256 blocks), fp32 out -> d_out
__global__ __launch_bounds__(256) void k_gemm_out64(
    const unsigned short* __restrict__ attnb, const unsigned short* __restrict__ WoT,
    float* __restrict__ out) {
  __shared__ unsigned short As[64 * 32];
  __shared__ unsigned short Bs[128 * 32];
  int m0 = blockIdx.x * 64, n0 = blockIdx.y * 128;
  const int tid = threadIdx.x, w = tid >> 6, lane = tid & 63;
  const int quad = lane >> 4, li = lane & 15, wr = w >> 1, wc = w & 1;
  f32x4 z = {0.f, 0.f, 0.f, 0.f};
  f32x4 acc[2][4];
#pragma unroll
  for (int mi = 0; mi < 2; ++mi)
#pragma unroll
    for (int ni = 0; ni < 4; ++ni) acc[mi][ni] = z;
  const int rs = lane >> 2, cs = lane & 3;
  for (int k0 = 0; k0 < 1024; k0 += 32) {
    __syncthreads();
    {
      int r = w * 16 + rs;
      int c = cs ^ ((r >> 1) & 3);
      gl2lds16(attnb + (size_t)(m0 + r) * 1024 + k0 + c * 8, (char*)As + w * 1024);
    }
#pragma unroll
    for (int s = 0; s < 2; ++s) {
      int i = w * 2 + s;
      int r = i * 16 + rs;
      int c = cs ^ ((r >> 1) & 3);
      gl2lds16(WoT + (size_t)(n0 + r) * 1024 + k0 + c * 8, (char*)Bs + i * 1024);
    }
    __syncthreads();
    bf16x8 af[2], bfr[4];
#pragma unroll
    for (int mi = 0; mi < 2; ++mi) {
      int r = wr * 32 + mi * 16 + li;
      int ch = quad ^ ((r >> 1) & 3);
      af[mi] = *(const bf16x8*)((const char*)As + r * 64 + ch * 16);
    }
#pragma unroll
    for (int ni = 0; ni < 4; ++ni) {
      int r = wc * 64 + ni * 16 + li;
      int ch = quad ^ ((r >> 1) & 3);
      bfr[ni] = *(const bf16x8*)((const char*)Bs + r * 64 + ch * 16);
    }
#pragma unroll
    for (int mi = 0; mi < 2; ++mi)
#pragma unroll
      for (int ni = 0; ni < 4; ++ni)
        acc[mi][ni] = __builtin_amdgcn_mfma_f32_16x16x32_bf16(
            af[mi], bfr[ni], acc[mi][ni], 0, 0, 0);
  }
#pragma unroll
  for (int mi = 0; mi < 2; ++mi)
#pragma unroll
    for (int ni = 0; ni < 4; ++ni)
#pragma unroll
      for (int reg = 0; reg < 4; ++reg) {
        int rrow = m0 + wr * 32 + mi * 16 + quad * 4 + reg;
        int cc = n0 + wc * 64 + ni * 16 + li;
        out[(size_t)rrow * 1024 + cc] = acc[mi][ni][reg];
      }
}

// ---------------- flash attention, single-barrier pipelined K-loop ----------
// R7 structure; q biases (r_w, r_r) now applied in-register from raw qb.
__global__ __launch_bounds__(256, 2) void k_attn(
    const unsigned short* __restrict__ qb, const float* __restrict__ rwb,
    const float* __restrict__ rrb,
    const unsigned short* __restrict__ kb, const unsigned short* __restrict__ vt,
    const unsigned short* __restrict__ rkb, const unsigned short* __restrict__ mb,
    unsigned short* __restrict__ attnb) {
  __shared__ unsigned short Ks[2][64 * 64];
  __shared__ unsigned short Vs[2][64 * 64];
  __shared__ unsigned short Rs[256 * 64];
  __shared__ unsigned short Sb[4][16 * 72];  // per-wave s (f16), [row][key]

  const int tid = threadIdx.x;
  const int w = tid >> 6, lane = tid & 63;
  const int quad = lane >> 4, li = lane & 15;
  const int qt = blockIdx.x, h = blockIdx.y, b = blockIdx.z;
  const int t0blk = qt * 64;
  const int t0w = t0blk + w * 16;
  const int rboff = 48 - 16 * w;
  const int rbase0 = Tq - t0blk - 63;

  bf16x8 aqw[2], aqr[2];
  {
    const unsigned short* p1 = qb + ((size_t)((b * Tq + t0w + li) * Hh + h)) * 64;
#pragma unroll
    for (int ks = 0; ks < 2; ++ks) {
      bf16x8 qf = *(const bf16x8*)(p1 + ks * 32 + quad * 8);
      const float* wp = rwb + h * 64 + ks * 32 + quad * 8;
      const float* rp = rrb + h * 64 + ks * 32 + quad * 8;
      float4 w0 = *(const float4*)wp, w1 = *(const float4*)(wp + 4);
      float4 r0 = *(const float4*)rp, r1 = *(const float4*)(rp + 4);
      float wv[8] = {w0.x, w0.y, w0.z, w0.w, w1.x, w1.y, w1.z, w1.w};
      float rv[8] = {r0.x, r0.y, r0.z, r0.w, r1.x, r1.y, r1.z, r1.w};
#pragma unroll
      for (int i2 = 0; i2 < 8; ++i2) {
        float qv = b2f((unsigned short)qf[i2]);
        aqw[ks][i2] = (short)f2bf(qv + wv[i2]);
        aqr[ks][i2] = (short)f2bf(qv + rv[i2]);
      }
    }
  }

  f32x4 z = {0.f, 0.f, 0.f, 0.f};
  f32x4 o[4];
  o[0] = z; o[1] = z; o[2] = z; o[3] = z;
  f32x4 ol = z;

  const int srow = lane >> 3;
  const int scs = lane & 7;
  const float SC = 0.125f * 1.4426950408889634f;
  const short oneb = 0x3F80;
  const bf16x8 onesf = {oneb, oneb, oneb, oneb, oneb, oneb, oneb, oneb};

  unsigned short* pw = &Sb[w][0];
  const unsigned short* mrowA = mb + ((size_t)(b * Tq + t0w + li)) * Ll;
  int srcl[4];
#pragma unroll
  for (int reg = 0; reg < 4; ++reg) {
    int row = quad * 4 + reg;
    srcl[reg] = (lane & 48) + ((li + row + 1) & 15);
  }

  // ---- preload: R ring rows [0,127]; K/V tile jt=0 into buffer 0 ----
#pragma unroll
  for (int s = 0; s < 4; ++s) {
    int i = w * 4 + s;
    int r = i * 8 + srow;
    int gr = rbase0 + r;
    if (gr > Rr - 1) gr = Rr - 1;
    int c = scs ^ (r & 7);
    gl2lds16(rkb + ((size_t)gr * Hh + h) * 64 + c * 8, (char*)Rs + i * 1024);
  }
#pragma unroll
  for (int s = 0; s < 2; ++s) {
    int i = w * 2 + s;
    int r = i * 8 + srow;
    int c = scs ^ (r & 7);
    gl2lds16(kb + ((size_t)((b * Ll + r) * Hh + h)) * 64 + c * 8,
             (char*)Ks[0] + i * 1024);
    gl2lds16(vt + ((size_t)((b * Hh + h) * 64 + r)) * Ll + c * 8,
             (char*)Vs[0] + i * 1024);
  }

  for (int jt = 0; jt < 32; ++jt) {
    const int j0 = jt * 64;
    const int cur = jt & 1, nxt = cur ^ 1;
    __builtin_amdgcn_s_waitcnt(0x0F70);  // vmcnt(0): prefetch complete
    __syncthreads();
    // ---- THIS jt's mask loads FIRST (oldest in vm queue) ----
    bf16x8 mv0 = *(const bf16x8*)(mrowA + j0 + quad * 8);
    bf16x8 mv1 = *(const bf16x8*)(mrowA + j0 + 32 + quad * 8);
    asm volatile("" ::: "memory");  // pin: mask issue precedes prefetch DMAs
    // ---- issue prefetch for jt+1 (drained at the NEXT barrier) ----
    if (jt < 31) {
      const int j0n = j0 + 64;
#pragma unroll
      for (int s = 0; s < 2; ++s) {
        int i = w * 2 + s;
        int r = i * 8 + srow;
        int c = scs ^ (r & 7);
        gl2lds16(kb + ((size_t)((b * Ll + j0n + r) * Hh + h)) * 64 + c * 8,
                 (char*)Ks[nxt] + i * 1024);
        gl2lds16(vt + ((size_t)((b * Hh + h) * 64 + r)) * Ll + j0n + c * 8,
                 (char*)Vs[nxt] + i * 1024);
      }
#pragma unroll
      for (int s = 0; s < 2; ++s) {
        int i2 = w * 2 + s;
        int rr = i2 * 8 + srow;
        int ofs = j0 + 128 + rr;
        int gr = rbase0 + ofs;
        if (gr > Rr - 1) gr = Rr - 1;
        int ring = ofs & 255;
        int c = scs ^ (rr & 7);
        gl2lds16(rkb + ((size_t)gr * Hh + h) * 64 + c * 8, (char*)Rs + ring * 128);
      }
    }
    // ---- compute jt from buffer `cur` ----
    const unsigned short* KsC = Ks[cur];
    const unsigned short* VsC = Vs[cur];
    f32x4 sc[4];
    sc[0] = z; sc[1] = z; sc[2] = z; sc[3] = z;
#pragma unroll
    for (int ks = 0; ks < 2; ++ks)
#pragma unroll
      for (int nt = 0; nt < 4; ++nt) {
        int j = nt * 16 + li;
        int ch = (ks * 4 + quad) ^ (j & 7);
        bf16x8 kf = *(const bf16x8*)((const char*)KsC + j * 128 + ch * 16);
        sc[nt] = __builtin_amdgcn_mfma_f32_16x16x32_bf16(aqw[ks], kf, sc[nt], 0, 0, 0);
      }
    f32x4 bd[5];
    bd[0] = z; bd[1] = z; bd[2] = z; bd[3] = z; bd[4] = z;
#pragma unroll
    for (int ks = 0; ks < 2; ++ks)
#pragma unroll
      for (int nt = 0; nt < 5; ++nt) {
        int pr = (rboff + nt * 16 + li + j0) & 255;
        int ch = (ks * 4 + quad) ^ (pr & 7);
        bf16x8 rf = *(const bf16x8*)((const char*)Rs + pr * 128 + ch * 16);
        bd[nt] = __builtin_amdgcn_mfma_f32_16x16x32_bf16(aqr[ks], rf, bd[nt], 0, 0, 0);
      }
    float rot[4][4];
#pragma unroll
    for (int nt = 0; nt < 4; ++nt)
#pragma unroll
      for (int reg = 0; reg < 4; ++reg)
        rot[nt][reg] = __shfl(sc[nt][reg], srcl[reg], 64);
#pragma unroll
    for (int nt = 0; nt < 5; ++nt)
#pragma unroll
      for (int reg = 0; reg < 4; ++reg) {
        int row = quad * 4 + reg;
        int jj = nt * 16 + li + row - 15;
        int ntlo = (nt == 0) ? 3 : (nt - 1);
        int nthi = (nt > 3) ? 0 : nt;
        float val = ((li + row) >= 15) ? rot[nthi][reg] : rot[ntlo][reg];
        float s = val + bd[nt][reg];
        if ((unsigned)jj < 64u)
          pw[row * 72 + jj] = __builtin_bit_cast(unsigned short, __float2half(s));
      }
    __builtin_amdgcn_s_waitcnt(0xc07f);  // lgkmcnt(0) only
#pragma unroll
    for (int ks = 0; ks < 2; ++ks) {
      const int cofs = ks * 32 + quad * 8;
      ushort4 s0 = *(const ushort4*)(pw + li * 72 + cofs);
      ushort4 s1 = *(const ushort4*)(pw + li * 72 + cofs + 4);
      bf16x8 mv = ks ? mv1 : mv0;
      unsigned short su[8] = {s0.x, s0.y, s0.z, s0.w, s1.x, s1.y, s1.z, s1.w};
      bf16x8 ap;
#pragma unroll
      for (int i2 = 0; i2 < 8; ++i2) {
        float sf = __half2float(__builtin_bit_cast(__half, su[i2]));
        float mvf = b2f((unsigned short)mv[i2]);
        float p = exp2f(sf * SC - mvf);
        ap[i2] = (short)f2bf(p);
      }
      ol = __builtin_amdgcn_mfma_f32_16x16x32_bf16(ap, onesf, ol, 0, 0, 0);
#pragma unroll
      for (int nt = 0; nt < 4; ++nt) {
        int dv = nt * 16 + li;
        int ch = (ks * 4 + quad) ^ (dv & 7);
        bf16x8 vf = *(const bf16x8*)((const char*)VsC + dv * 128 + ch * 16);
        o[nt] = __builtin_amdgcn_mfma_f32_16x16x32_bf16(ap, vf, o[nt], 0, 0, 0);
      }
    }
  }
  float inv[4];
#pragma unroll
  for (int reg = 0; reg < 4; ++reg) inv[reg] = 1.0f / ol[reg];
#pragma unroll
  for (int nt = 0; nt < 4; ++nt)
#pragma unroll
    for (int reg = 0; reg < 4; ++reg) {
      int trow = t0w + quad * 4 + reg;
      attnb[((size_t)(b * Tq + trow)) * 1024 + h * 64 + nt * 16 + li] =
          f2bf(o[nt][reg] * inv[reg]);
    }
}

extern "C" void kernel_launch(void* const* d_in, const int* in_sizes, int n_in,
                              void* d_out, int out_size, void* d_ws, size_t ws_size,
                              hipStream_t stream) {
  const float* x = (const float*)d_in[0];
  const float* mask = (const float*)d_in[1];
  const float* pos = (const float*)d_in[2];
  const float* mem = (const float*)d_in[3];
  const float* Wq = (const float*)d_in[4];
  const float* Wk = (const float*)d_in[5];
  const float* Wv = (const float*)d_in[6];
  const float* Wr = (const float*)d_in[7];
  const float* rwb = (const float*)d_in[8];
  const float* rrb = (const float*)d_in[9];
  const float* Wo = (const float*)d_in[10];
  float* out = (float*)d_out;

  uint8_t* ws = (uint8_t*)d_ws;
  const size_t MB = 1024 * 1024;
  unsigned short* Vinb = (unsigned short*)(ws + 0);        // 8 MB (dead post-proj)
  unsigned short* WqT = (unsigned short*)(ws + 8 * MB);
  unsigned short* WkT = (unsigned short*)(ws + 10 * MB);
  unsigned short* WvT = (unsigned short*)(ws + 12 * MB);
  unsigned short* WrT = (unsigned short*)(ws + 14 * MB);
  unsigned short* WoT = (unsigned short*)(ws + 16 * MB);   // live to end
  unsigned short* Pb = (unsigned short*)(ws + 18 * MB);    // dead post-proj
  unsigned short* qb = (unsigned short*)(ws + 24 * MB);    // 4 MB raw q
  unsigned short* kb = (unsigned short*)(ws + 32 * MB);
  unsigned short* vtb = (unsigned short*)(ws + 40 * MB);   // [B][H][64][2048]
  unsigned short* rkb = (unsigned short*)(ws + 48 * MB);   // 6 MB
  unsigned short* mbb = (unsigned short*)(ws + 54 * MB);   // 8 MB mask bias bf16
  unsigned short* attnb = (unsigned short*)(ws + 19 * MB); // 4 MB (in Pb region)

  hipLaunchKernelGGL(k_prep2, dim3(12544), dim3(256), 0, stream,
                     x, mem, pos, mask, Wq, Wk, Wv, Wr, Wo,
                     Vinb, Pb, mbb, WqT, WkT, WvT, WrT, WoT);
  hipLaunchKernelGGL(k_proj, dim3(576), dim3(256), 0, stream,
                     Vinb, Pb, WqT, WkT, WvT, WrT, qb, kb, vtb, rkb);
  hipLaunchKernelGGL(k_attn, dim3(16, 16, 2), dim3(256), 0, stream,
                     qb, rwb, rrb, kb, vtb, rkb, mbb, attnb);
  hipLaunchKernelGGL(k_gemm_out64, dim3(32, 8), dim3(256), 0, stream,
                     attnb, WoT, out);
}

// Round 9
// 262.071 us; speedup vs baseline: 1.0276x; 1.0276x over previous
//
#include <hip/hip_runtime.h>
#include <hip/hip_fp16.h>
#include <stdint.h>

#define Bz 2
#define Tq 1024
#define Mm 1024
#define Hh 16
#define Ll 2048
#define Rr 3072

typedef __attribute__((ext_vector_type(8))) short bf16x8;
typedef __attribute__((ext_vector_type(4))) float f32x4;

typedef __attribute__((address_space(3))) uint8_t lds_u8_t;
typedef __attribute__((address_space(1))) uint8_t glb_u8_t;

__device__ __forceinline__ void gl2lds16(const void* g, void* l) {
  __builtin_amdgcn_global_load_lds((const glb_u8_t*)g, (lds_u8_t*)l, 16, 0, 0);
}

__device__ __forceinline__ unsigned short f2bf(float f) {
  unsigned int u = __builtin_bit_cast(unsigned int, f);
  u = u + 0x7fffu + ((u >> 16) & 1u);
  return (unsigned short)(u >> 16);
}
__device__ __forceinline__ float b2f(unsigned short s) {
  unsigned int u = ((unsigned int)s) << 16;
  return __builtin_bit_cast(float, u);
}

// ------- prep (merged): values cast | pos cast | mask bias | 5x W transpose -
__global__ __launch_bounds__(256) void k_prep2(
    const float* __restrict__ x, const float* __restrict__ mem,
    const float* __restrict__ pos, const float* __restrict__ mask,
    const float* __restrict__ w0, const float* __restrict__ w1,
    const float* __restrict__ w2, const float* __restrict__ w3,
    const float* __restrict__ w4,
    unsigned short* __restrict__ vin, unsigned short* __restrict__ pb,
    unsigned short* __restrict__ mb,
    unsigned short* __restrict__ t0, unsigned short* __restrict__ t1,
    unsigned short* __restrict__ t2, unsigned short* __restrict__ t3,
    unsigned short* __restrict__ t4) {
  __shared__ float tile[64][65];
  int bid = blockIdx.x;
  if (bid < 4096) {
    int idx = bid * 256 + threadIdx.x;
    int e = idx << 2;
    int row = e >> 10, col = e & 1023;
    int b = row >> 11, l = row & 2047;
    const float* s = (l < Mm) ? (mem + (((size_t)b * Mm + l) << 10) + col)
                              : (x + (((size_t)b * Tq + (l - Mm)) << 10) + col);
    float4 v = *(const float4*)s;
    ushort4 o;
    o.x = f2bf(v.x); o.y = f2bf(v.y); o.z = f2bf(v.z); o.w = f2bf(v.w);
    *(ushort4*)(vin + e) = o;
  } else if (bid < 7168) {
    int idx = (bid - 4096) * 256 + threadIdx.x;
    int e = idx << 2;
    float4 v = *(const float4*)(pos + e);
    ushort4 t;
    t.x = f2bf(v.x); t.y = f2bf(v.y); t.z = f2bf(v.z); t.w = f2bf(v.w);
    *(ushort4*)(pb + e) = t;
  } else if (bid < 11264) {
    int idx = (bid - 7168) * 256 + threadIdx.x;
    int e = idx << 2;
    const float BIGM = 1.442695e30f;
    float4 v = *(const float4*)(mask + e);
    ushort4 t;
    t.x = f2bf((1.0f - v.x) * BIGM); t.y = f2bf((1.0f - v.y) * BIGM);
    t.z = f2bf((1.0f - v.z) * BIGM); t.w = f2bf((1.0f - v.w) * BIGM);
    *(ushort4*)(mb + e) = t;
  } else {
    int r3 = bid - 11264;
    int mz = r3 >> 8, rem = r3 & 255;
    const float* W;
    unsigned short* WT;
    switch (mz) {
      case 0: W = w0; WT = t0; break;
      case 1: W = w1; WT = t1; break;
      case 2: W = w2; WT = t2; break;
      case 3: W = w3; WT = t3; break;
      default: W = w4; WT = t4; break;
    }
    int k0 = (rem >> 4) * 64, n0 = (rem & 15) * 64;
    int tid = threadIdx.x;
    int rr = tid >> 4, c4 = (tid & 15) * 4;
#pragma unroll
    for (int it = 0; it < 4; ++it) {
      int r = rr + it * 16;
      float4 v = *(const float4*)(W + (size_t)(k0 + r) * 1024 + n0 + c4);
      tile[r][c4] = v.x; tile[r][c4 + 1] = v.y;
      tile[r][c4 + 2] = v.z; tile[r][c4 + 3] = v.w;
    }
    __syncthreads();
#pragma unroll
    for (int it = 0; it < 4; ++it) {
      int n = rr + it * 16;
      ushort4 o;
      o.x = f2bf(tile[c4 + 0][n]); o.y = f2bf(tile[c4 + 1][n]);
      o.z = f2bf(tile[c4 + 2][n]); o.w = f2bf(tile[c4 + 3][n]);
      *(ushort4*)(WT + (size_t)(n0 + n) * 1024 + k0 + c4) = o;
    }
  }
}

// ------- bf16 NT GEMM core, single-barrier pipelined, dbuf LDS (K=1024) -----
// Per iter: vmcnt(0)+barrier drains the DMAs issued a FULL iteration earlier
// (compute gave them cover); issue next K-tile into the other buffer; compute
// current. As/Bs are [2][128*32] ushorts (16 KB each).
template <int RMAP>
__device__ __forceinline__ void gemm_pipe(const unsigned short* __restrict__ A,
                                          const unsigned short* __restrict__ Bt,
                                          int m0, int n0, unsigned short* As,
                                          unsigned short* Bs, f32x4 acc[4][4]) {
  const int tid = threadIdx.x;
  const int w = tid >> 6, lane = tid & 63;
  const int quad = lane >> 4, li = lane & 15;
  const int wr = w >> 1, wc = w & 1;
  f32x4 z = {0.f, 0.f, 0.f, 0.f};
#pragma unroll
  for (int mi = 0; mi < 4; ++mi)
#pragma unroll
    for (int ni = 0; ni < 4; ++ni) acc[mi][ni] = z;

  const int rs = lane >> 2;
  const int cs = lane & 3;

  // preload k0=0 into buffer 0
#pragma unroll
  for (int s = 0; s < 2; ++s) {
    int i = w * 2 + s;
    int r = i * 16 + rs;
    int c = cs ^ ((r >> 1) & 3);
    int ar = m0 + r;
    if (RMAP) ar = ar + 1024 + (ar & 1024);
    gl2lds16(A + (size_t)ar * 1024 + c * 8, (char*)As + i * 1024);
    gl2lds16(Bt + (size_t)(n0 + r) * 1024 + c * 8, (char*)Bs + i * 1024);
  }

  for (int k0 = 0; k0 < 1024; k0 += 32) {
    const int bo = ((k0 >> 5) & 1) * 8192;  // current buffer byte offset
    const int no = bo ^ 8192;               // next buffer
    __builtin_amdgcn_s_waitcnt(0x0F70);     // vmcnt(0)
    __syncthreads();
    if (k0 + 32 < 1024) {
#pragma unroll
      for (int s = 0; s < 2; ++s) {
        int i = w * 2 + s;
        int r = i * 16 + rs;
        int c = cs ^ ((r >> 1) & 3);
        int ar = m0 + r;
        if (RMAP) ar = ar + 1024 + (ar & 1024);
        gl2lds16(A + (size_t)ar * 1024 + k0 + 32 + c * 8,
                 (char*)As + no + i * 1024);
        gl2lds16(Bt + (size_t)(n0 + r) * 1024 + k0 + 32 + c * 8,
                 (char*)Bs + no + i * 1024);
      }
    }
    bf16x8 af[4], bfr[4];
#pragma unroll
    for (int mi = 0; mi < 4; ++mi) {
      int r = wr * 64 + mi * 16 + li;
      int ch = quad ^ ((r >> 1) & 3);
      af[mi] = *(const bf16x8*)((const char*)As + bo + r * 64 + ch * 16);
    }
#pragma unroll
    for (int ni = 0; ni < 4; ++ni) {
      int r = wc * 64 + ni * 16 + li;
      int ch = quad ^ ((r >> 1) & 3);
      bfr[ni] = *(const bf16x8*)((const char*)Bs + bo + r * 64 + ch * 16);
    }
#pragma unroll
    for (int mi = 0; mi < 4; ++mi)
#pragma unroll
      for (int ni = 0; ni < 4; ++ni)
        acc[mi][ni] = __builtin_amdgcn_mfma_f32_16x16x32_bf16(
            af[mi], bfr[ni], acc[mi][ni], 0, 0, 0);
  }
}

// fused projections (uniform 128x128 blocks, pipelined core):
// [0,256) k | [256,512) v -> vtb direct-transposed | [512,640) q raw |
// [640,832) rk.
__global__ __launch_bounds__(256) void k_proj(
    const unsigned short* __restrict__ Vin, const unsigned short* __restrict__ Pb,
    const unsigned short* __restrict__ WqT, const unsigned short* __restrict__ WkT,
    const unsigned short* __restrict__ WvT, const unsigned short* __restrict__ WrT,
    unsigned short* __restrict__ qb, unsigned short* __restrict__ kb,
    unsigned short* __restrict__ vtb, unsigned short* __restrict__ rkb) {
  __shared__ unsigned short As[2 * 128 * 32];
  __shared__ unsigned short Bs[2 * 128 * 32];
  const int t = blockIdx.x;
  const int tid = threadIdx.x, w = tid >> 6, lane = tid & 63;
  const int quad = lane >> 4, li = lane & 15, wr = w >> 1, wc = w & 1;
  f32x4 acc[4][4];

  if (t < 256) {  // k
    int m0 = (t >> 3) * 128, n0 = (t & 7) * 128;
    gemm_pipe<0>(Vin, WkT, m0, n0, As, Bs, acc);
#pragma unroll
    for (int mi = 0; mi < 4; ++mi)
#pragma unroll
      for (int ni = 0; ni < 4; ++ni)
#pragma unroll
        for (int reg = 0; reg < 4; ++reg) {
          int rrow = m0 + wr * 64 + mi * 16 + quad * 4 + reg;
          int cc = n0 + wc * 64 + ni * 16 + li;
          kb[(size_t)rrow * 1024 + cc] = f2bf(acc[mi][ni][reg]);
        }
  } else if (t < 512) {  // v -> vtb[b,h*64+dv, l] (ushort4 over l)
    int tt = t - 256;
    int m0 = (tt >> 3) * 128, n0 = (tt & 7) * 128;
    gemm_pipe<0>(Vin, WvT, m0, n0, As, Bs, acc);
#pragma unroll
    for (int mi = 0; mi < 4; ++mi)
#pragma unroll
      for (int ni = 0; ni < 4; ++ni) {
        int r0 = m0 + wr * 64 + mi * 16 + quad * 4;
        int b = r0 >> 11, l0 = r0 & 2047;
        int cc = n0 + wc * 64 + ni * 16 + li;
        ushort4 o;
        o.x = f2bf(acc[mi][ni][0]); o.y = f2bf(acc[mi][ni][1]);
        o.z = f2bf(acc[mi][ni][2]); o.w = f2bf(acc[mi][ni][3]);
        *(ushort4*)(vtb + ((size_t)(b * 1024 + cc)) * Ll + l0) = o;
      }
  } else if (t < 640) {  // q raw
    int tt = t - 512;
    int m0 = (tt >> 3) * 128, n0 = (tt & 7) * 128;
    gemm_pipe<1>(Vin, WqT, m0, n0, As, Bs, acc);
#pragma unroll
    for (int mi = 0; mi < 4; ++mi)
#pragma unroll
      for (int ni = 0; ni < 4; ++ni)
#pragma unroll
        for (int reg = 0; reg < 4; ++reg) {
          int rrow = m0 + wr * 64 + mi * 16 + quad * 4 + reg;
          int cc = n0 + wc * 64 + ni * 16 + li;
          qb[(size_t)rrow * 1024 + cc] = f2bf(acc[mi][ni][reg]);
        }
  } else {  // rk
    int tt = t - 640;
    int m0 = (tt >> 3) * 128, n0 = (tt & 7) * 128;
    gemm_pipe<0>(Pb, WrT, m0, n0, As, Bs, acc);
#pragma unroll
    for (int mi = 0; mi < 4; ++mi)
#pragma unroll
      for (int ni = 0; ni < 4; ++ni)
#pragma unroll
        for (int reg = 0; reg < 4; ++reg) {
          int rrow = m0 + wr * 64 + mi * 16 + quad * 4 + reg;
          int cc = n0 + wc * 64 + ni * 16 + li;
          rkb[(size_t)rrow * 1024 + cc] = f2bf(acc[mi][ni][reg]);
        }
  }
}

// output projection, 64x128 tile, pipelined, fp32 out -> d_out
__global__ __launch_bounds__(256) void k_gemm_out64(
    const unsigned short* __restrict__ attnb, const unsigned short* __restrict__ WoT,
    float* __restrict__ out) {
  __shared__ unsigned short As[2 * 64 * 32];
  __shared__ unsigned short Bs[2 * 128 * 32];
  int m0 = blockIdx.x * 64, n0 = blockIdx.y * 128;
  const int tid = threadIdx.x, w = tid >> 6, lane = tid & 63;
  const int quad = lane >> 4, li = lane & 15, wr = w >> 1, wc = w & 1;
  f32x4 z = {0.f, 0.f, 0.f, 0.f};
  f32x4 acc[2][4];
#pragma unroll
  for (int mi = 0; mi < 2; ++mi)
#pragma unroll
    for (int ni = 0; ni < 4; ++ni) acc[mi][ni] = z;
  const int rs = lane >> 2, cs = lane & 3;

  // preload k0=0
  {
    int r = w * 16 + rs;
    int c = cs ^ ((r >> 1) & 3);
    gl2lds16(attnb + (size_t)(m0 + r) * 1024 + c * 8, (char*)As + w * 1024);
  }
#pragma unroll
  for (int s = 0; s < 2; ++s) {
    int i = w * 2 + s;
    int r = i * 16 + rs;
    int c = cs ^ ((r >> 1) & 3);
    gl2lds16(WoT + (size_t)(n0 + r) * 1024 + c * 8, (char*)Bs + i * 1024);
  }

  for (int k0 = 0; k0 < 1024; k0 += 32) {
    const int boa = ((k0 >> 5) & 1) * 4096;
    const int bob = ((k0 >> 5) & 1) * 8192;
    __builtin_amdgcn_s_waitcnt(0x0F70);
    __syncthreads();
    if (k0 + 32 < 1024) {
      {
        int r = w * 16 + rs;
        int c = cs ^ ((r >> 1) & 3);
        gl2lds16(attnb + (size_t)(m0 + r) * 1024 + k0 + 32 + c * 8,
                 (char*)As + (boa ^ 4096) + w * 1024);
      }
#pragma unroll
      for (int s = 0; s < 2; ++s) {
        int i = w * 2 + s;
        int r = i * 16 + rs;
        int c = cs ^ ((r >> 1) & 3);
        gl2lds16(WoT + (size_t)(n0 + r) * 1024 + k0 + 32 + c * 8,
                 (char*)Bs + (bob ^ 8192) + i * 1024);
      }
    }
    bf16x8 af[2], bfr[4];
#pragma unroll
    for (int mi = 0; mi < 2; ++mi) {
      int r = wr * 32 + mi * 16 + li;
      int ch = quad ^ ((r >> 1) & 3);
      af[mi] = *(const bf16x8*)((const char*)As + boa + r * 64 + ch * 16);
    }
#pragma unroll
    for (int ni = 0; ni < 4; ++ni) {
      int r = wc * 64 + ni * 16 + li;
      int ch = quad ^ ((r >> 1) & 3);
      bfr[ni] = *(const bf16x8*)((const char*)Bs + bob + r * 64 + ch * 16);
    }
#pragma unroll
    for (int mi = 0; mi < 2; ++mi)
#pragma unroll
      for (int ni = 0; ni < 4; ++ni)
        acc[mi][ni] = __builtin_amdgcn_mfma_f32_16x16x32_bf16(
            af[mi], bfr[ni], acc[mi][ni], 0, 0, 0);
  }
#pragma unroll
  for (int mi = 0; mi < 2; ++mi)
#pragma unroll
    for (int ni = 0; ni < 4; ++ni)
#pragma unroll
      for (int reg = 0; reg < 4; ++reg) {
        int rrow = m0 + wr * 32 + mi * 16 + quad * 4 + reg;
        int cc = n0 + wc * 64 + ni * 16 + li;
        out[(size_t)rrow * 1024 + cc] = acc[mi][ni][reg];
      }
}

// ---------------- flash attention (R7 structure, bias-in-register q) --------
__global__ __launch_bounds__(256, 2) void k_attn(
    const unsigned short* __restrict__ qb, const float* __restrict__ rwb,
    const float* __restrict__ rrb,
    const unsigned short* __restrict__ kb, const unsigned short* __restrict__ vt,
    const unsigned short* __restrict__ rkb, const unsigned short* __restrict__ mb,
    unsigned short* __restrict__ attnb) {
  __shared__ unsigned short Ks[2][64 * 64];
  __shared__ unsigned short Vs[2][64 * 64];
  __shared__ unsigned short Rs[256 * 64];
  __shared__ unsigned short Sb[4][16 * 72];

  const int tid = threadIdx.x;
  const int w = tid >> 6, lane = tid & 63;
  const int quad = lane >> 4, li = lane & 15;
  const int qt = blockIdx.x, h = blockIdx.y, b = blockIdx.z;
  const int t0blk = qt * 64;
  const int t0w = t0blk + w * 16;
  const int rboff = 48 - 16 * w;
  const int rbase0 = Tq - t0blk - 63;

  bf16x8 aqw[2], aqr[2];
  {
    const unsigned short* p1 = qb + ((size_t)((b * Tq + t0w + li) * Hh + h)) * 64;
#pragma unroll
    for (int ks = 0; ks < 2; ++ks) {
      bf16x8 qf = *(const bf16x8*)(p1 + ks * 32 + quad * 8);
      const float* wp = rwb + h * 64 + ks * 32 + quad * 8;
      const float* rp = rrb + h * 64 + ks * 32 + quad * 8;
      float4 w0 = *(const float4*)wp, w1 = *(const float4*)(wp + 4);
      float4 r0 = *(const float4*)rp, r1 = *(const float4*)(rp + 4);
      float wv[8] = {w0.x, w0.y, w0.z, w0.w, w1.x, w1.y, w1.z, w1.w};
      float rv[8] = {r0.x, r0.y, r0.z, r0.w, r1.x, r1.y, r1.z, r1.w};
#pragma unroll
      for (int i2 = 0; i2 < 8; ++i2) {
        float qv = b2f((unsigned short)qf[i2]);
        aqw[ks][i2] = (short)f2bf(qv + wv[i2]);
        aqr[ks][i2] = (short)f2bf(qv + rv[i2]);
      }
    }
  }

  f32x4 z = {0.f, 0.f, 0.f, 0.f};
  f32x4 o[4];
  o[0] = z; o[1] = z; o[2] = z; o[3] = z;
  f32x4 ol = z;

  const int srow = lane >> 3;
  const int scs = lane & 7;
  const float SC = 0.125f * 1.4426950408889634f;
  const short oneb = 0x3F80;
  const bf16x8 onesf = {oneb, oneb, oneb, oneb, oneb, oneb, oneb, oneb};

  unsigned short* pw = &Sb[w][0];
  const unsigned short* mrowA = mb + ((size_t)(b * Tq + t0w + li)) * Ll;
  int srcl[4];
#pragma unroll
  for (int reg = 0; reg < 4; ++reg) {
    int row = quad * 4 + reg;
    srcl[reg] = (lane & 48) + ((li + row + 1) & 15);
  }

#pragma unroll
  for (int s = 0; s < 4; ++s) {
    int i = w * 4 + s;
    int r = i * 8 + srow;
    int gr = rbase0 + r;
    if (gr > Rr - 1) gr = Rr - 1;
    int c = scs ^ (r & 7);
    gl2lds16(rkb + ((size_t)gr * Hh + h) * 64 + c * 8, (char*)Rs + i * 1024);
  }
#pragma unroll
  for (int s = 0; s < 2; ++s) {
    int i = w * 2 + s;
    int r = i * 8 + srow;
    int c = scs ^ (r & 7);
    gl2lds16(kb + ((size_t)((b * Ll + r) * Hh + h)) * 64 + c * 8,
             (char*)Ks[0] + i * 1024);
    gl2lds16(vt + ((size_t)((b * Hh + h) * 64 + r)) * Ll + c * 8,
             (char*)Vs[0] + i * 1024);
  }

  for (int jt = 0; jt < 32; ++jt) {
    const int j0 = jt * 64;
    const int cur = jt & 1, nxt = cur ^ 1;
    __builtin_amdgcn_s_waitcnt(0x0F70);
    __syncthreads();
    bf16x8 mv0 = *(const bf16x8*)(mrowA + j0 + quad * 8);
    bf16x8 mv1 = *(const bf16x8*)(mrowA + j0 + 32 + quad * 8);
    asm volatile("" ::: "memory");
    if (jt < 31) {
      const int j0n = j0 + 64;
#pragma unroll
      for (int s = 0; s < 2; ++s) {
        int i = w * 2 + s;
        int r = i * 8 + srow;
        int c = scs ^ (r & 7);
        gl2lds16(kb + ((size_t)((b * Ll + j0n + r) * Hh + h)) * 64 + c * 8,
                 (char*)Ks[nxt] + i * 1024);
        gl2lds16(vt + ((size_t)((b * Hh + h) * 64 + r)) * Ll + j0n + c * 8,
                 (char*)Vs[nxt] + i * 1024);
      }
#pragma unroll
      for (int s = 0; s < 2; ++s) {
        int i2 = w * 2 + s;
        int rr = i2 * 8 + srow;
        int ofs = j0 + 128 + rr;
        int gr = rbase0 + ofs;
        if (gr > Rr - 1) gr = Rr - 1;
        int ring = ofs & 255;
        int c = scs ^ (rr & 7);
        gl2lds16(rkb + ((size_t)gr * Hh + h) * 64 + c * 8, (char*)Rs + ring * 128);
      }
    }
    const unsigned short* KsC = Ks[cur];
    const unsigned short* VsC = Vs[cur];
    f32x4 sc[4];
    sc[0] = z; sc[1] = z; sc[2] = z; sc[3] = z;
#pragma unroll
    for (int ks = 0; ks < 2; ++ks)
#pragma unroll
      for (int nt = 0; nt < 4; ++nt) {
        int j = nt * 16 + li;
        int ch = (ks * 4 + quad) ^ (j & 7);
        bf16x8 kf = *(const bf16x8*)((const char*)KsC + j * 128 + ch * 16);
        sc[nt] = __builtin_amdgcn_mfma_f32_16x16x32_bf16(aqw[ks], kf, sc[nt], 0, 0, 0);
      }
    f32x4 bd[5];
    bd[0] = z; bd[1] = z; bd[2] = z; bd[3] = z; bd[4] = z;
#pragma unroll
    for (int ks = 0; ks < 2; ++ks)
#pragma unroll
      for (int nt = 0; nt < 5; ++nt) {
        int pr = (rboff + nt * 16 + li + j0) & 255;
        int ch = (ks * 4 + quad) ^ (pr & 7);
        bf16x8 rf = *(const bf16x8*)((const char*)Rs + pr * 128 + ch * 16);
        bd[nt] = __builtin_amdgcn_mfma_f32_16x16x32_bf16(aqr[ks], rf, bd[nt], 0, 0, 0);
      }
    float rot[4][4];
#pragma unroll
    for (int nt = 0; nt < 4; ++nt)
#pragma unroll
      for (int reg = 0; reg < 4; ++reg)
        rot[nt][reg] = __shfl(sc[nt][reg], srcl[reg], 64);
#pragma unroll
    for (int nt = 0; nt < 5; ++nt)
#pragma unroll
      for (int reg = 0; reg < 4; ++reg) {
        int row = quad * 4 + reg;
        int jj = nt * 16 + li + row - 15;
        int ntlo = (nt == 0) ? 3 : (nt - 1);
        int nthi = (nt > 3) ? 0 : nt;
        float val = ((li + row) >= 15) ? rot[nthi][reg] : rot[ntlo][reg];
        float s = val + bd[nt][reg];
        if ((unsigned)jj < 64u)
          pw[row * 72 + jj] = __builtin_bit_cast(unsigned short, __float2half(s));
      }
    __builtin_amdgcn_s_waitcnt(0xc07f);
#pragma unroll
    for (int ks = 0; ks < 2; ++ks) {
      const int cofs = ks * 32 + quad * 8;
      ushort4 s0 = *(const ushort4*)(pw + li * 72 + cofs);
      ushort4 s1 = *(const ushort4*)(pw + li * 72 + cofs + 4);
      bf16x8 mv = ks ? mv1 : mv0;
      unsigned short su[8] = {s0.x, s0.y, s0.z, s0.w, s1.x, s1.y, s1.z, s1.w};
      bf16x8 ap;
#pragma unroll
      for (int i2 = 0; i2 < 8; ++i2) {
        float sf = __half2float(__builtin_bit_cast(__half, su[i2]));
        float mvf = b2f((unsigned short)mv[i2]);
        float p = exp2f(sf * SC - mvf);
        ap[i2] = (short)f2bf(p);
      }
      ol = __builtin_amdgcn_mfma_f32_16x16x32_bf16(ap, onesf, ol, 0, 0, 0);
#pragma unroll
      for (int nt = 0; nt < 4; ++nt) {
        int dv = nt * 16 + li;
        int ch = (ks * 4 + quad) ^ (dv & 7);
        bf16x8 vf = *(const bf16x8*)((const char*)VsC + dv * 128 + ch * 16);
        o[nt] = __builtin_amdgcn_mfma_f32_16x16x32_bf16(ap, vf, o[nt], 0, 0, 0);
      }
    }
  }
  float inv[4];
#pragma unroll
  for (int reg = 0; reg < 4; ++reg) inv[reg] = 1.0f / ol[reg];
#pragma unroll
  for (int nt = 0; nt < 4; ++nt)
#pragma unroll
    for (int reg = 0; reg < 4; ++reg) {
      int trow = t0w + quad * 4 + reg;
      attnb[((size_t)(b * Tq + trow)) * 1024 + h * 64 + nt * 16 + li] =
          f2bf(o[nt][reg] * inv[reg]);
    }
}

extern "C" void kernel_launch(void* const* d_in, const int* in_sizes, int n_in,
                              void* d_out, int out_size, void* d_ws, size_t ws_size,
                              hipStream_t stream) {
  const float* x = (const float*)d_in[0];
  const float* mask = (const float*)d_in[1];
  const float* pos = (const float*)d_in[2];
  const float* mem = (const float*)d_in[3];
  const float* Wq = (const float*)d_in[4];
  const float* Wk = (const float*)d_in[5];
  const float* Wv = (const float*)d_in[6];
  const float* Wr = (const float*)d_in[7];
  const float* rwb = (const float*)d_in[8];
  const float* rrb = (const float*)d_in[9];
  const float* Wo = (const float*)d_in[10];
  float* out = (float*)d_out;

  uint8_t* ws = (uint8_t*)d_ws;
  const size_t MB = 1024 * 1024;
  unsigned short* Vinb = (unsigned short*)(ws + 0);
  unsigned short* WqT = (unsigned short*)(ws + 8 * MB);
  unsigned short* WkT = (unsigned short*)(ws + 10 * MB);
  unsigned short* WvT = (unsigned short*)(ws + 12 * MB);
  unsigned short* WrT = (unsigned short*)(ws + 14 * MB);
  unsigned short* WoT = (unsigned short*)(ws + 16 * MB);
  unsigned short* Pb = (unsigned short*)(ws + 18 * MB);
  unsigned short* qb = (unsigned short*)(ws + 24 * MB);
  unsigned short* kb = (unsigned short*)(ws + 32 * MB);
  unsigned short* vtb = (unsigned short*)(ws + 40 * MB);
  unsigned short* rkb = (unsigned short*)(ws + 48 * MB);
  unsigned short* mbb = (unsigned short*)(ws + 54 * MB);
  unsigned short* attnb = (unsigned short*)(ws + 19 * MB);

  hipLaunchKernelGGL(k_prep2, dim3(12544), dim3(256), 0, stream,
                     x, mem, pos, mask, Wq, Wk, Wv, Wr, Wo,
                     Vinb, Pb, mbb, WqT, WkT, WvT, WrT, WoT);
  hipLaunchKernelGGL(k_proj, dim3(832), dim3(256), 0, stream,
                     Vinb, Pb, WqT, WkT, WvT, WrT, qb, kb, vtb, rkb);
  hipLaunchKernelGGL(k_attn, dim3(16, 16, 2), dim3(256), 0, stream,
                     qb, rwb, rrb, kb, vtb, rkb, mbb, attnb);
  hipLaunchKernelGGL(k_gemm_out64, dim3(32, 8), dim3(256), 0, stream,
                     attnb, WoT, out);
}